// Round 1
// baseline (154.004 us; speedup 1.0000x reference)
//
#include <hip/hip_runtime.h>

// GaussianRegLoss: mean over [bs, nj, h, w, d] of
//   (exp(-||grid - kpt||^2)/(2*sigma^2) - sigmoid(heatmap))^2
// bs=4, nj=23, h=w=d=64, sigma=5 -> 1/(2*25) = 0.02
// Inputs (setup_inputs order): 0=kpts_gt (UNUSED), 1=kpts_pred [bs,3,nj],
//   2=heatmaps [bs,nj,h,w,d], 3=grids [bs,h*w*d,3]. Output: 1 float.

#define HWD   262144          // 64*64*64
#define NJ    23
#define BS    4
#define NTOT  24117248.0      // BS*NJ*HWD
#define BLK   256
#define VPT   4               // voxels per thread
#define NBLOCKS 1024          // BS*HWD / (BLK*VPT)

__global__ __launch_bounds__(BLK) void gauss_loss_main(
    const float* __restrict__ kpts_pred,   // [BS,3,NJ]
    const float* __restrict__ heatmaps,    // [BS,NJ,HWD]
    const float* __restrict__ grids,       // [BS,HWD,3]
    float* __restrict__ partials)          // [NBLOCKS]
{
    const int t  = blockIdx.x * BLK + threadIdx.x;
    const int v4 = t * VPT;                // first voxel of this thread (global over BS*HWD)
    const int b  = v4 >> 18;               // / HWD  (block-uniform: 256 blocks per b)
    const int x4 = v4 & (HWD - 1);

    // stage this batch's 69 keypoint coords in LDS (broadcast reads later)
    __shared__ float s_c[3 * NJ];
    if (threadIdx.x < 3 * NJ) s_c[threadIdx.x] = kpts_pred[b * 3 * NJ + threadIdx.x];
    __syncthreads();

    // grids for 4 voxels: 12 contiguous floats, 16B-aligned (48B offset granularity)
    const float* gp = grids + (size_t)(b * HWD + x4) * 3;
    const float4 g0 = *reinterpret_cast<const float4*>(gp);
    const float4 g1 = *reinterpret_cast<const float4*>(gp + 4);
    const float4 g2 = *reinterpret_cast<const float4*>(gp + 8);
    const float gx[VPT] = {g0.x, g0.w, g1.z, g2.y};
    const float gy[VPT] = {g0.y, g1.x, g1.w, g2.z};
    const float gz[VPT] = {g0.z, g1.y, g2.x, g2.w};

    const float LOG2E = 1.4426950408889634f;
    const float* hmbase = heatmaps + (size_t)b * NJ * HWD + x4;

    float acc = 0.f;
    for (int j = 0; j < NJ; ++j) {
        const float cx = s_c[j], cy = s_c[NJ + j], cz = s_c[2 * NJ + j];
        const float4 hm = *reinterpret_cast<const float4*>(hmbase + (size_t)j * HWD);
        const float hmv[VPT] = {hm.x, hm.y, hm.z, hm.w};
        #pragma unroll
        for (int i = 0; i < VPT; ++i) {
            const float dx = gx[i] - cx, dy = gy[i] - cy, dz = gz[i] - cz;
            const float sq = dx * dx + dy * dy + dz * dz;
            // exp(-sq)/50 = exp2(-sq*log2e) * 0.02
            const float gauss = __builtin_amdgcn_exp2f(-sq * LOG2E) * 0.02f;
            // sigmoid(hm) = 1/(1+exp(-hm))
            const float e   = __builtin_amdgcn_exp2f(-hmv[i] * LOG2E);
            const float sig = __builtin_amdgcn_rcpf(1.0f + e);
            const float d = gauss - sig;
            acc += d * d;
        }
    }

    // wave (64) reduce, then cross-wave via LDS
    #pragma unroll
    for (int off = 32; off > 0; off >>= 1)
        acc += __shfl_down(acc, off, 64);
    __shared__ float s_w[BLK / 64];
    const int lane = threadIdx.x & 63, wid = threadIdx.x >> 6;
    if (lane == 0) s_w[wid] = acc;
    __syncthreads();
    if (threadIdx.x == 0)
        partials[blockIdx.x] = s_w[0] + s_w[1] + s_w[2] + s_w[3];
}

__global__ __launch_bounds__(BLK) void gauss_loss_reduce(
    const float* __restrict__ partials, float* __restrict__ out, int n)
{
    double acc = 0.0;
    for (int i = threadIdx.x; i < n; i += BLK) acc += (double)partials[i];
    #pragma unroll
    for (int off = 32; off > 0; off >>= 1)
        acc += __shfl_down(acc, off, 64);
    __shared__ double s_w[BLK / 64];
    const int lane = threadIdx.x & 63, wid = threadIdx.x >> 6;
    if (lane == 0) s_w[wid] = acc;
    __syncthreads();
    if (threadIdx.x == 0)
        out[0] = (float)((s_w[0] + s_w[1] + s_w[2] + s_w[3]) / NTOT);
}

extern "C" void kernel_launch(void* const* d_in, const int* in_sizes, int n_in,
                              void* d_out, int out_size, void* d_ws, size_t ws_size,
                              hipStream_t stream) {
    // input order per setup_inputs: 0=kpts_gt (unused), 1=kpts_pred, 2=heatmaps, 3=grids
    const float* kpts_pred = (const float*)d_in[1];
    const float* heatmaps  = (const float*)d_in[2];
    const float* grids     = (const float*)d_in[3];
    float* out      = (float*)d_out;
    float* partials = (float*)d_ws;   // NBLOCKS floats (ws re-poisoned each call; fully overwritten)

    gauss_loss_main<<<NBLOCKS, BLK, 0, stream>>>(kpts_pred, heatmaps, grids, partials);
    gauss_loss_reduce<<<1, BLK, 0, stream>>>(partials, out, NBLOCKS);
}